// Round 8
// baseline (188.188 us; speedup 1.0000x reference)
//
#include <hip/hip_runtime.h>

namespace {
constexpr int N_NODES = 100000;
constexpr int N_EDGES = 640000;
constexpr int SCAN_B = 1024;
constexpr int NSCANB = (N_NODES + SCAN_B - 1) / SCAN_B;  // 98
constexpr int ROWTILES = N_NODES / 16;                   // 6250 (exact)
}

typedef short bf16x8 __attribute__((ext_vector_type(8)));
typedef float f32x4 __attribute__((ext_vector_type(4)));

static __device__ inline uint32_t cvt_pk_bf16(float a, float b) {
  uint32_t r;
  asm volatile("v_cvt_pk_bf16_f32 %0, %1, %2" : "=v"(r) : "v"(a), "v"(b));
  return r;  // lo = bf16(a) RNE, hi = bf16(b)
}

// 8 bf16 (uint4) -> 8 f32
static __device__ inline void bf8_to_f32(uint4 u, float* v) {
  v[0] = __uint_as_float(u.x << 16);
  v[1] = __uint_as_float(u.x & 0xffff0000u);
  v[2] = __uint_as_float(u.y << 16);
  v[3] = __uint_as_float(u.y & 0xffff0000u);
  v[4] = __uint_as_float(u.z << 16);
  v[5] = __uint_as_float(u.z & 0xffff0000u);
  v[6] = __uint_as_float(u.w << 16);
  v[7] = __uint_as_float(u.w & 0xffff0000u);
}

static __device__ inline uint4 f32_to_bf8(const float* v) {
  uint4 o;
  o.x = cvt_pk_bf16(v[0], v[1]);
  o.y = cvt_pk_bf16(v[2], v[3]);
  o.z = cvt_pk_bf16(v[4], v[5]);
  o.w = cvt_pk_bf16(v[6], v[7]);
  return o;
}

// ---------------- CSR build ----------------

__global__ void k_hist(const int* __restrict__ col, int* __restrict__ deg) {
  int i = blockIdx.x * 256 + threadIdx.x;
  if (i < N_EDGES) atomicAdd(&deg[col[i]], 1);
}

// window-local (1024 nodes) counting sort by degree -> perm (bijection).
// Equal-degree nodes land in the same 16-node wave stripe => no intra-wave
// divergence in the gather loops; every window has the same degree mix =>
// block-level load balance, no drain tail.
__global__ __launch_bounds__(256) void k_sortperm(const int* __restrict__ deg,
                                                  int* __restrict__ perm) {
  __shared__ int hist[64];
  __shared__ int cur[64];
  int t = threadIdx.x;
  int base = blockIdx.x * SCAN_B;
  int nvalid = min(SCAN_B, N_NODES - base);
  if (t < 64) hist[t] = 0;
  __syncthreads();
  int d[4];
#pragma unroll
  for (int j = 0; j < 4; ++j) {
    int g = t * 4 + j;
    d[j] = -1;
    if (g < nvalid) {
      d[j] = min(deg[base + g], 63);
      atomicAdd(&hist[d[j]], 1);
    }
  }
  __syncthreads();
  if (t < 64) cur[t] = hist[t];
  __syncthreads();
  for (int s = 1; s < 64; s <<= 1) {
    int add = 0;
    if (t < 64 && t >= s) add = cur[t - s];
    __syncthreads();
    if (t < 64) cur[t] += add;
    __syncthreads();
  }
  if (t < 64) cur[t] -= hist[t];  // exclusive scan
  __syncthreads();
#pragma unroll
  for (int j = 0; j < 4; ++j) {
    if (d[j] >= 0) {
      int pos = atomicAdd(&cur[d[j]], 1);
      perm[base + pos] = base + t * 4 + j;
    }
  }
}

__global__ __launch_bounds__(256) void k_scan1(const int* __restrict__ deg,
                                               int* __restrict__ excl,
                                               int* __restrict__ bsum) {
  __shared__ int tmp[256];
  int t = threadIdx.x;
  int base = blockIdx.x * SCAN_B + t * 4;
  int v[4];
#pragma unroll
  for (int j = 0; j < 4; ++j) {
    int g = base + j;
    v[j] = (g < N_NODES) ? deg[g] : 0;
  }
  int s = v[0] + v[1] + v[2] + v[3];
  tmp[t] = s;
  __syncthreads();
  for (int d = 1; d < 256; d <<= 1) {
    int add = (t >= d) ? tmp[t - d] : 0;
    __syncthreads();
    tmp[t] += add;
    __syncthreads();
  }
  int off = tmp[t] - s;
#pragma unroll
  for (int j = 0; j < 4; ++j) {
    int g = base + j;
    if (g < N_NODES) excl[g] = off;
    off += v[j];
  }
  if (t == 255) bsum[blockIdx.x] = tmp[255];
}

__global__ __launch_bounds__(128) void k_scan2(int* __restrict__ bsum) {
  __shared__ int tmp[128];
  int t = threadIdx.x;
  int v = (t < NSCANB) ? bsum[t] : 0;
  tmp[t] = v;
  __syncthreads();
  for (int d = 1; d < 128; d <<= 1) {
    int add = (t >= d) ? tmp[t - d] : 0;
    __syncthreads();
    tmp[t] += add;
    __syncthreads();
  }
  if (t < NSCANB) bsum[t] = tmp[t] - v;  // exclusive
}

__global__ void k_scan3(const int* __restrict__ excl, const int* __restrict__ bsum,
                        const int* __restrict__ deg, int* __restrict__ cursor,
                        float* __restrict__ dinv) {
  int i = blockIdx.x * 256 + threadIdx.x;
  if (i < N_NODES) {
    cursor[i] = excl[i] + bsum[i / SCAN_B];
    dinv[i] = rsqrtf((float)deg[i] + 1.0f);
  }
}

__global__ void k_fill(const int* __restrict__ row, const int* __restrict__ col,
                       int* __restrict__ cursor, int* __restrict__ csr_src) {
  int e = blockIdx.x * 256 + threadIdx.x;
  if (e < N_EDGES) {
    int pos = atomicAdd(&cursor[col[e]], 1);
    csr_src[pos] = row[e];
  }
}
// after k_fill: cursor[n] = end of n's range; start = cursor[n] - deg[n]

// ---------------- W prep: per-lane bf16 MFMA B-fragments ----------------

static __device__ inline void wpack(const float* __restrict__ W, int kout, int idx,
                                    uint4* __restrict__ wfrag) {
  int nt_cnt = kout / 16;
  int lane = idx & 63;
  int nt = (idx >> 6) % nt_cnt;
  int ks = idx / (64 * nt_cnt);
  int g = lane >> 4, c = lane & 15;
  const float* wp = W + (ks * 32 + g * 8) * kout + nt * 16 + c;
  float w[8];
#pragma unroll
  for (int j = 0; j < 8; ++j) w[j] = wp[j * kout];
  wfrag[idx] = f32_to_bf8(w);
}

__global__ void k_wprep_all(const float* __restrict__ W1, const float* __restrict__ W2,
                            uint4* __restrict__ wf1, uint4* __restrict__ wf2) {
  int idx = blockIdx.x * 256 + threadIdx.x;
  if (idx < 2048) {
    wpack(W1, 128, idx, wf1);
  } else if (idx < 3072) {
    wpack(W2, 64, idx - 2048, wf2);
  }
}

// ---------------- MFMA GEMM 1: hs1[n,:] = bf16( dinv[n] * (x[n,:] @ W1) ) ----------

__global__ __launch_bounds__(256) void k_gemm1(const float* __restrict__ X,
                                               const uint4* __restrict__ wfrag,
                                               const float* __restrict__ dinv,
                                               unsigned short* __restrict__ Yb) {
  constexpr int NT = 8;
  const int tid = threadIdx.x;
  const int w = blockIdx.x * 4 + (tid >> 6);
  if (w >= ROWTILES) return;
  const int lane = tid & 63;
  const int g = lane >> 4, c = lane & 15;
  const int rb = w * 16;

  f32x4 acc[NT];
#pragma unroll
  for (int nt = 0; nt < NT; ++nt) acc[nt] = (f32x4){0.f, 0.f, 0.f, 0.f};

  const bf16x8* wf = (const bf16x8*)wfrag;
  const float* xrow = X + (long long)(rb + c) * 128 + g * 8;

#pragma unroll
  for (int ks = 0; ks < 4; ++ks) {
    float4 a0 = *(const float4*)(xrow + ks * 32);
    float4 a1 = *(const float4*)(xrow + ks * 32 + 4);
    union { bf16x8 v; uint32_t u[4]; } af;
    af.u[0] = cvt_pk_bf16(a0.x, a0.y);
    af.u[1] = cvt_pk_bf16(a0.z, a0.w);
    af.u[2] = cvt_pk_bf16(a1.x, a1.y);
    af.u[3] = cvt_pk_bf16(a1.z, a1.w);
#pragma unroll
    for (int nt = 0; nt < NT; ++nt) {
      bf16x8 bf = wf[(ks * NT + nt) * 64 + lane];
      acc[nt] = __builtin_amdgcn_mfma_f32_16x16x32_bf16(af.v, bf, acc[nt], 0, 0, 0);
    }
  }

  // C/D layout (m89-verified): col = lane&15, row = (lane>>4)*4 + reg
#pragma unroll
  for (int r = 0; r < 4; ++r) {
    int row = rb + g * 4 + r;
    float s = dinv[row];
#pragma unroll
    for (int nt = 0; nt < NT; ++nt) {
      float val = acc[nt][r] * s;
      Yb[(long long)row * 128 + nt * 16 + c] = (unsigned short)cvt_pk_bf16(val, val);
    }
  }
}

// ---------------- FUSED: layer-1 aggregation + layer-2 GEMM (perm-ordered) ----------

__global__ __launch_bounds__(256) void k_gather_gemm2(
    const int* __restrict__ perm, const int* __restrict__ cursor,
    const int* __restrict__ deg, const int* __restrict__ csr_src,
    const float* __restrict__ dinv, const unsigned short* __restrict__ hs1,
    const float* __restrict__ b1, const uint4* __restrict__ wfrag2,
    unsigned short* __restrict__ hs2) {
  const int tid = threadIdx.x;
  const int w = blockIdx.x * 4 + (tid >> 6);
  if (w >= ROWTILES) return;
  const int lane = tid & 63;
  const int g = lane >> 4, c = lane & 15;
  const int rb = w * 16;
  const int n = perm[rb + c];  // degree-sorted slot -> node
  const float d = dinv[n];
  const int end = cursor[n];
  const int dg = deg[n];

  float acc[4][8];
  {  // self term
    const unsigned short* hrow = hs1 + (long long)n * 128 + g * 8;
#pragma unroll
    for (int ks = 0; ks < 4; ++ks) bf8_to_f32(*(const uint4*)(hrow + ks * 32), acc[ks]);
  }

  int s = end - dg;
  for (; s + 2 <= end; s += 2) {
    int s0 = csr_src[s], s1 = csr_src[s + 1];
    const unsigned short* p0 = hs1 + (long long)s0 * 128 + g * 8;
    const unsigned short* p1 = hs1 + (long long)s1 * 128 + g * 8;
#pragma unroll
    for (int ks = 0; ks < 4; ++ks) {
      float v0[8], v1[8];
      bf8_to_f32(*(const uint4*)(p0 + ks * 32), v0);
      bf8_to_f32(*(const uint4*)(p1 + ks * 32), v1);
#pragma unroll
      for (int j = 0; j < 8; ++j) acc[ks][j] += v0[j] + v1[j];
    }
  }
  if (s < end) {
    const unsigned short* p0 = hs1 + (long long)csr_src[s] * 128 + g * 8;
#pragma unroll
    for (int ks = 0; ks < 4; ++ks) {
      float v0[8];
      bf8_to_f32(*(const uint4*)(p0 + ks * 32), v0);
#pragma unroll
      for (int j = 0; j < 8; ++j) acc[ks][j] += v0[j];
    }
  }

  // agg1 row slice = relu(b1 + d*acc) -> bf16 A-fragments
  union { bf16x8 v; uint32_t u[4]; } av[4];
#pragma unroll
  for (int ks = 0; ks < 4; ++ks) {
    float4 bv0 = *(const float4*)&b1[ks * 32 + g * 8];
    float4 bv1 = *(const float4*)&b1[ks * 32 + g * 8 + 4];
    float r8[8];
    r8[0] = fmaxf(bv0.x + d * acc[ks][0], 0.f);
    r8[1] = fmaxf(bv0.y + d * acc[ks][1], 0.f);
    r8[2] = fmaxf(bv0.z + d * acc[ks][2], 0.f);
    r8[3] = fmaxf(bv0.w + d * acc[ks][3], 0.f);
    r8[4] = fmaxf(bv1.x + d * acc[ks][4], 0.f);
    r8[5] = fmaxf(bv1.y + d * acc[ks][5], 0.f);
    r8[6] = fmaxf(bv1.z + d * acc[ks][6], 0.f);
    r8[7] = fmaxf(bv1.w + d * acc[ks][7], 0.f);
    av[ks].u[0] = cvt_pk_bf16(r8[0], r8[1]);
    av[ks].u[1] = cvt_pk_bf16(r8[2], r8[3]);
    av[ks].u[2] = cvt_pk_bf16(r8[4], r8[5]);
    av[ks].u[3] = cvt_pk_bf16(r8[6], r8[7]);
  }

  // layer-2 MFMA: hs2 rows (node ids via perm) = dinv * (agg1 @ W2)
  f32x4 accm[4];
#pragma unroll
  for (int nt = 0; nt < 4; ++nt) accm[nt] = (f32x4){0.f, 0.f, 0.f, 0.f};
  const bf16x8* wf = (const bf16x8*)wfrag2;
#pragma unroll
  for (int ks = 0; ks < 4; ++ks) {
#pragma unroll
    for (int nt = 0; nt < 4; ++nt) {
      bf16x8 bf = wf[(ks * 4 + nt) * 64 + lane];
      accm[nt] = __builtin_amdgcn_mfma_f32_16x16x32_bf16(av[ks].v, bf, accm[nt], 0, 0, 0);
    }
  }

#pragma unroll
  for (int r = 0; r < 4; ++r) {
    int row = perm[rb + g * 4 + r];
    float sc = dinv[row];
#pragma unroll
    for (int nt = 0; nt < 4; ++nt) {
      float val = accm[nt][r] * sc;
      hs2[(long long)row * 64 + nt * 16 + c] = (unsigned short)cvt_pk_bf16(val, val);
    }
  }
}

// ---- final gather (perm-ordered): out[n] = b2 + dinv[n]*(hs2[n] + sum_src hs2[src]) ----

__global__ __launch_bounds__(256) void k_gather_out(
    const int* __restrict__ perm, const int* __restrict__ cursor,
    const int* __restrict__ deg, const int* __restrict__ csr_src,
    const float* __restrict__ dinv, const unsigned short* __restrict__ hs,
    const float* __restrict__ bias, float* __restrict__ out) {
  constexpr int C = 64, Q = 8;
  int idx = blockIdx.x * 256 + threadIdx.x;
  if (idx >= N_NODES * Q) return;
  int n = perm[idx / Q];
  int q = idx % Q;
  float d = dinv[n];
  int end = cursor[n];
  int dg = deg[n];

  float acc[8];
  bf8_to_f32(*(const uint4*)&hs[(long long)n * C + q * 8], acc);  // self term

  int s = end - dg;
  for (; s + 2 <= end; s += 2) {
    int s0 = csr_src[s], s1 = csr_src[s + 1];
    uint4 u0 = *(const uint4*)&hs[(long long)s0 * C + q * 8];
    uint4 u1 = *(const uint4*)&hs[(long long)s1 * C + q * 8];
    float v0[8], v1[8];
    bf8_to_f32(u0, v0);
    bf8_to_f32(u1, v1);
#pragma unroll
    for (int j = 0; j < 8; ++j) acc[j] += v0[j] + v1[j];
  }
  if (s < end) {
    float v0[8];
    bf8_to_f32(*(const uint4*)&hs[(long long)csr_src[s] * C + q * 8], v0);
#pragma unroll
    for (int j = 0; j < 8; ++j) acc[j] += v0[j];
  }

  float4 bv0 = *(const float4*)&bias[q * 8];
  float4 bv1 = *(const float4*)&bias[q * 8 + 4];
  float4 o0 = {bv0.x + d * acc[0], bv0.y + d * acc[1], bv0.z + d * acc[2],
               bv0.w + d * acc[3]};
  float4 o1 = {bv1.x + d * acc[4], bv1.y + d * acc[5], bv1.z + d * acc[6],
               bv1.w + d * acc[7]};
  *(float4*)&out[(long long)n * C + q * 8] = o0;
  *(float4*)&out[(long long)n * C + q * 8 + 4] = o1;
}

// ---------------- launch ----------------

extern "C" void kernel_launch(void* const* d_in, const int* in_sizes, int n_in,
                              void* d_out, int out_size, void* d_ws, size_t ws_size,
                              hipStream_t stream) {
  const float* x = (const float*)d_in[0];
  const int* ei = (const int*)d_in[1];
  const int* erow = ei;            // sources
  const int* ecol = ei + N_EDGES;  // targets
  const float* W1 = (const float*)d_in[2];
  const float* b1 = (const float*)d_in[3];
  const float* W2 = (const float*)d_in[4];
  const float* b2 = (const float*)d_in[5];
  float* out = (float*)d_out;

  char* ws = (char*)d_ws;
  int* deg = (int*)(ws + 0);                     // 400,000 B
  int* cursor = (int*)(ws + 400128);             // 400,000 B
  int* excl = (int*)(ws + 800256);               // 400,000 B
  int* bsum = (int*)(ws + 1200384);              // 512 B
  int* csr_src = (int*)(ws + 1200896);           // 2,560,000 B
  float* dinv = (float*)(ws + 3760896);          // 400,000 B
  int* perm = (int*)(ws + 4161024);              // 400,000 B
  unsigned short* hs1 = (unsigned short*)(ws + 4561152);  // 25.6 MB (bf16)
  unsigned short* hs2 = (unsigned short*)(ws + 30161152); // 12.8 MB (bf16)
  uint4* wfrag1 = (uint4*)(ws + 42961152);       // 32 KB
  uint4* wfrag2 = (uint4*)(ws + 42993920);       // 16 KB

  hipMemsetAsync(deg, 0, N_NODES * sizeof(int), stream);
  k_wprep_all<<<12, 256, 0, stream>>>(W1, W2, wfrag1, wfrag2);

  // CSR build + degree-sorted permutation
  k_hist<<<(N_EDGES + 255) / 256, 256, 0, stream>>>(ecol, deg);
  k_sortperm<<<NSCANB, 256, 0, stream>>>(deg, perm);
  k_scan1<<<NSCANB, 256, 0, stream>>>(deg, excl, bsum);
  k_scan2<<<1, 128, 0, stream>>>(bsum);
  k_scan3<<<(N_NODES + 255) / 256, 256, 0, stream>>>(excl, bsum, deg, cursor, dinv);
  k_fill<<<(N_EDGES + 255) / 256, 256, 0, stream>>>(erow, ecol, cursor, csr_src);

  const int gblocks = (ROWTILES + 3) / 4;  // 1563

  // layer 1 GEMM -> hs1 (bf16)
  k_gemm1<<<gblocks, 256, 0, stream>>>(x, wfrag1, dinv, hs1);
  // fused layer-1 aggregation + layer-2 GEMM -> hs2 (bf16)
  k_gather_gemm2<<<gblocks, 256, 0, stream>>>(perm, cursor, deg, csr_src, dinv, hs1, b1,
                                              wfrag2, hs2);
  // final aggregation -> out (f32)
  k_gather_out<<<N_NODES * 8 / 256, 256, 0, stream>>>(perm, cursor, deg, csr_src, dinv,
                                                      hs2, b2, out);
}

// Round 9
// 171.274 us; speedup vs baseline: 1.0988x; 1.0988x over previous
//
#include <hip/hip_runtime.h>

namespace {
constexpr int N_NODES = 100000;
constexpr int N_EDGES = 640000;
constexpr int SCAN_B = 1024;
constexpr int NSCANB = (N_NODES + SCAN_B - 1) / SCAN_B;  // 98
constexpr int ROWTILES = N_NODES / 16;                   // 6250 (exact)
}

typedef short bf16x8 __attribute__((ext_vector_type(8)));
typedef float f32x4 __attribute__((ext_vector_type(4)));

static __device__ inline uint32_t cvt_pk_bf16(float a, float b) {
  uint32_t r;
  asm volatile("v_cvt_pk_bf16_f32 %0, %1, %2" : "=v"(r) : "v"(a), "v"(b));
  return r;  // lo = bf16(a) RNE, hi = bf16(b)
}

// 8 bf16 (uint4) -> 8 f32
static __device__ inline void bf8_to_f32(uint4 u, float* v) {
  v[0] = __uint_as_float(u.x << 16);
  v[1] = __uint_as_float(u.x & 0xffff0000u);
  v[2] = __uint_as_float(u.y << 16);
  v[3] = __uint_as_float(u.y & 0xffff0000u);
  v[4] = __uint_as_float(u.z << 16);
  v[5] = __uint_as_float(u.z & 0xffff0000u);
  v[6] = __uint_as_float(u.w << 16);
  v[7] = __uint_as_float(u.w & 0xffff0000u);
}

static __device__ inline uint4 f32_to_bf8(const float* v) {
  uint4 o;
  o.x = cvt_pk_bf16(v[0], v[1]);
  o.y = cvt_pk_bf16(v[2], v[3]);
  o.z = cvt_pk_bf16(v[4], v[5]);
  o.w = cvt_pk_bf16(v[6], v[7]);
  return o;
}

// ---------------- CSR build ----------------

__global__ void k_hist(const int* __restrict__ col, int* __restrict__ deg) {
  int i = blockIdx.x * 256 + threadIdx.x;
  if (i < N_EDGES) atomicAdd(&deg[col[i]], 1);
}

__global__ __launch_bounds__(256) void k_scan1(const int* __restrict__ deg,
                                               int* __restrict__ excl,
                                               int* __restrict__ bsum) {
  __shared__ int tmp[256];
  int t = threadIdx.x;
  int base = blockIdx.x * SCAN_B + t * 4;
  int v[4];
#pragma unroll
  for (int j = 0; j < 4; ++j) {
    int g = base + j;
    v[j] = (g < N_NODES) ? deg[g] : 0;
  }
  int s = v[0] + v[1] + v[2] + v[3];
  tmp[t] = s;
  __syncthreads();
  for (int d = 1; d < 256; d <<= 1) {
    int add = (t >= d) ? tmp[t - d] : 0;
    __syncthreads();
    tmp[t] += add;
    __syncthreads();
  }
  int off = tmp[t] - s;
#pragma unroll
  for (int j = 0; j < 4; ++j) {
    int g = base + j;
    if (g < N_NODES) excl[g] = off;
    off += v[j];
  }
  if (t == 255) bsum[blockIdx.x] = tmp[255];
}

__global__ __launch_bounds__(128) void k_scan2(int* __restrict__ bsum) {
  __shared__ int tmp[128];
  int t = threadIdx.x;
  int v = (t < NSCANB) ? bsum[t] : 0;
  tmp[t] = v;
  __syncthreads();
  for (int d = 1; d < 128; d <<= 1) {
    int add = (t >= d) ? tmp[t - d] : 0;
    __syncthreads();
    tmp[t] += add;
    __syncthreads();
  }
  if (t < NSCANB) bsum[t] = tmp[t] - v;  // exclusive
}

__global__ void k_scan3(const int* __restrict__ excl, const int* __restrict__ bsum,
                        const int* __restrict__ deg, int* __restrict__ cursor,
                        float* __restrict__ dinv) {
  int i = blockIdx.x * 256 + threadIdx.x;
  if (i < N_NODES) {
    cursor[i] = excl[i] + bsum[i / SCAN_B];
    dinv[i] = rsqrtf((float)deg[i] + 1.0f);
  }
}

__global__ void k_fill(const int* __restrict__ row, const int* __restrict__ col,
                       int* __restrict__ cursor, int* __restrict__ csr_src) {
  int e = blockIdx.x * 256 + threadIdx.x;
  if (e < N_EDGES) {
    int pos = atomicAdd(&cursor[col[e]], 1);
    csr_src[pos] = row[e];
  }
}
// after k_fill: cursor[n] = end of n's range; start = cursor[n] - deg[n]

// ---------------- W prep: per-lane bf16 MFMA B-fragments ----------------

static __device__ inline void wpack(const float* __restrict__ W, int kout, int idx,
                                    uint4* __restrict__ wfrag) {
  int nt_cnt = kout / 16;
  int lane = idx & 63;
  int nt = (idx >> 6) % nt_cnt;
  int ks = idx / (64 * nt_cnt);
  int g = lane >> 4, c = lane & 15;
  const float* wp = W + (ks * 32 + g * 8) * kout + nt * 16 + c;
  float w[8];
#pragma unroll
  for (int j = 0; j < 8; ++j) w[j] = wp[j * kout];
  wfrag[idx] = f32_to_bf8(w);
}

__global__ void k_wprep_all(const float* __restrict__ W1, const float* __restrict__ W2,
                            uint4* __restrict__ wf1, uint4* __restrict__ wf2) {
  int idx = blockIdx.x * 256 + threadIdx.x;
  if (idx < 2048) {
    wpack(W1, 128, idx, wf1);
  } else if (idx < 3072) {
    wpack(W2, 64, idx - 2048, wf2);
  }
}

// ---------------- MFMA GEMM 1: hs1[n,:] = bf16( dinv[n] * (x[n,:] @ W1) ) ----------

__global__ __launch_bounds__(256) void k_gemm1(const float* __restrict__ X,
                                               const uint4* __restrict__ wfrag,
                                               const float* __restrict__ dinv,
                                               unsigned short* __restrict__ Yb) {
  constexpr int NT = 8;
  const int tid = threadIdx.x;
  const int w = blockIdx.x * 4 + (tid >> 6);
  if (w >= ROWTILES) return;
  const int lane = tid & 63;
  const int g = lane >> 4, c = lane & 15;
  const int rb = w * 16;

  f32x4 acc[NT];
#pragma unroll
  for (int nt = 0; nt < NT; ++nt) acc[nt] = (f32x4){0.f, 0.f, 0.f, 0.f};

  const bf16x8* wf = (const bf16x8*)wfrag;
  const float* xrow = X + (long long)(rb + c) * 128 + g * 8;

#pragma unroll
  for (int ks = 0; ks < 4; ++ks) {
    float4 a0 = *(const float4*)(xrow + ks * 32);
    float4 a1 = *(const float4*)(xrow + ks * 32 + 4);
    union { bf16x8 v; uint32_t u[4]; } af;
    af.u[0] = cvt_pk_bf16(a0.x, a0.y);
    af.u[1] = cvt_pk_bf16(a0.z, a0.w);
    af.u[2] = cvt_pk_bf16(a1.x, a1.y);
    af.u[3] = cvt_pk_bf16(a1.z, a1.w);
#pragma unroll
    for (int nt = 0; nt < NT; ++nt) {
      bf16x8 bf = wf[(ks * NT + nt) * 64 + lane];
      acc[nt] = __builtin_amdgcn_mfma_f32_16x16x32_bf16(af.v, bf, acc[nt], 0, 0, 0);
    }
  }

  // C/D layout (m89-verified): col = lane&15, row = (lane>>4)*4 + reg
#pragma unroll
  for (int r = 0; r < 4; ++r) {
    int row = rb + g * 4 + r;
    float s = dinv[row];
#pragma unroll
    for (int nt = 0; nt < NT; ++nt) {
      float val = acc[nt][r] * s;
      Yb[(long long)row * 128 + nt * 16 + c] = (unsigned short)cvt_pk_bf16(val, val);
    }
  }
}

// ---------------- FUSED: layer-1 aggregation + layer-2 GEMM ----------------
// Wave owns 16 contiguous nodes. Lane l: node n = rb+(l&15), k-slice (l>>4)*8.
// Edge gather uses a masked fixed-8 batch: all csr reads issued in parallel,
// then all row loads in parallel (2 dependent memory stages for deg<=8, ~80%
// of nodes); mask-FMA keeps arithmetic bit-identical to a sequential sum.

__global__ __launch_bounds__(256) void k_gather_gemm2(
    const int* __restrict__ cursor, const int* __restrict__ deg,
    const int* __restrict__ csr_src, const float* __restrict__ dinv,
    const unsigned short* __restrict__ hs1, const float* __restrict__ b1,
    const uint4* __restrict__ wfrag2, unsigned short* __restrict__ hs2) {
  const int tid = threadIdx.x;
  const int w = blockIdx.x * 4 + (tid >> 6);
  if (w >= ROWTILES) return;
  const int lane = tid & 63;
  const int g = lane >> 4, c = lane & 15;
  const int rb = w * 16;
  const int n = rb + c;
  const float d = dinv[n];
  const int end = cursor[n];
  const int dg = deg[n];

  float acc[4][8];
  {  // self term
    const unsigned short* hrow = hs1 + (long long)n * 128 + g * 8;
#pragma unroll
    for (int ks = 0; ks < 4; ++ks) bf8_to_f32(*(const uint4*)(hrow + ks * 32), acc[ks]);
  }

  if (dg > 0) {
    const int s0 = end - dg;
    int ids[8];
    float msk[8];
#pragma unroll
    for (int j = 0; j < 8; ++j) {
      ids[j] = csr_src[min(s0 + j, end - 1)];  // 8 independent L2 reads
      msk[j] = (j < dg) ? 1.0f : 0.0f;
    }
#pragma unroll
    for (int ks = 0; ks < 4; ++ks) {
      uint4 u[8];
#pragma unroll
      for (int j = 0; j < 8; ++j)
        u[j] = *(const uint4*)(hs1 + (long long)ids[j] * 128 + g * 8 + ks * 32);
#pragma unroll
      for (int j = 0; j < 8; ++j) {
        float v[8];
        bf8_to_f32(u[j], v);
#pragma unroll
        for (int t = 0; t < 8; ++t) acc[ks][t] = fmaf(msk[j], v[t], acc[ks][t]);
      }
    }
    // tail: deg > 8 (~20% of nodes)
    for (int s = s0 + 8; s < end; ++s) {
      const unsigned short* p0 = hs1 + (long long)csr_src[s] * 128 + g * 8;
#pragma unroll
      for (int ks = 0; ks < 4; ++ks) {
        float v0[8];
        bf8_to_f32(*(const uint4*)(p0 + ks * 32), v0);
#pragma unroll
        for (int t = 0; t < 8; ++t) acc[ks][t] += v0[t];
      }
    }
  }

  // agg1 row slice = relu(b1 + d*acc) -> bf16 A-fragments
  union { bf16x8 v; uint32_t u[4]; } av[4];
#pragma unroll
  for (int ks = 0; ks < 4; ++ks) {
    float4 bv0 = *(const float4*)&b1[ks * 32 + g * 8];
    float4 bv1 = *(const float4*)&b1[ks * 32 + g * 8 + 4];
    float r8[8];
    r8[0] = fmaxf(bv0.x + d * acc[ks][0], 0.f);
    r8[1] = fmaxf(bv0.y + d * acc[ks][1], 0.f);
    r8[2] = fmaxf(bv0.z + d * acc[ks][2], 0.f);
    r8[3] = fmaxf(bv0.w + d * acc[ks][3], 0.f);
    r8[4] = fmaxf(bv1.x + d * acc[ks][4], 0.f);
    r8[5] = fmaxf(bv1.y + d * acc[ks][5], 0.f);
    r8[6] = fmaxf(bv1.z + d * acc[ks][6], 0.f);
    r8[7] = fmaxf(bv1.w + d * acc[ks][7], 0.f);
    av[ks].u[0] = cvt_pk_bf16(r8[0], r8[1]);
    av[ks].u[1] = cvt_pk_bf16(r8[2], r8[3]);
    av[ks].u[2] = cvt_pk_bf16(r8[4], r8[5]);
    av[ks].u[3] = cvt_pk_bf16(r8[6], r8[7]);
  }

  // layer-2 MFMA: hs2 stripe = dinv * (agg1 @ W2)
  f32x4 accm[4];
#pragma unroll
  for (int nt = 0; nt < 4; ++nt) accm[nt] = (f32x4){0.f, 0.f, 0.f, 0.f};
  const bf16x8* wf = (const bf16x8*)wfrag2;
#pragma unroll
  for (int ks = 0; ks < 4; ++ks) {
#pragma unroll
    for (int nt = 0; nt < 4; ++nt) {
      bf16x8 bf = wf[(ks * 4 + nt) * 64 + lane];
      accm[nt] = __builtin_amdgcn_mfma_f32_16x16x32_bf16(av[ks].v, bf, accm[nt], 0, 0, 0);
    }
  }

#pragma unroll
  for (int r = 0; r < 4; ++r) {
    int row = rb + g * 4 + r;
    float sc = dinv[row];
#pragma unroll
    for (int nt = 0; nt < 4; ++nt) {
      float val = accm[nt][r] * sc;
      hs2[(long long)row * 64 + nt * 16 + c] = (unsigned short)cvt_pk_bf16(val, val);
    }
  }
}

// ---- final gather: out[n] = b2 + dinv[n]*(hs2[n] + sum_src hs2[src]), f32 out ----

__global__ __launch_bounds__(256) void k_gather_out(
    const int* __restrict__ cursor, const int* __restrict__ deg,
    const int* __restrict__ csr_src, const float* __restrict__ dinv,
    const unsigned short* __restrict__ hs, const float* __restrict__ bias,
    float* __restrict__ out) {
  constexpr int C = 64, Q = 8;
  int idx = blockIdx.x * 256 + threadIdx.x;
  if (idx >= N_NODES * Q) return;
  int n = idx / Q, q = idx % Q;
  float d = dinv[n];
  int end = cursor[n];
  int dg = deg[n];

  float acc[8];
  bf8_to_f32(*(const uint4*)&hs[(long long)n * C + q * 8], acc);  // self term

  if (dg > 0) {
    const int s0 = end - dg;
    int ids[8];
    float msk[8];
#pragma unroll
    for (int j = 0; j < 8; ++j) {
      ids[j] = csr_src[min(s0 + j, end - 1)];
      msk[j] = (j < dg) ? 1.0f : 0.0f;
    }
    uint4 u[8];
#pragma unroll
    for (int j = 0; j < 8; ++j)
      u[j] = *(const uint4*)&hs[(long long)ids[j] * C + q * 8];
#pragma unroll
    for (int j = 0; j < 8; ++j) {
      float v[8];
      bf8_to_f32(u[j], v);
#pragma unroll
      for (int t = 0; t < 8; ++t) acc[t] = fmaf(msk[j], v[t], acc[t]);
    }
    for (int s = s0 + 8; s < end; ++s) {
      float v[8];
      bf8_to_f32(*(const uint4*)&hs[(long long)csr_src[s] * C + q * 8], v);
#pragma unroll
      for (int t = 0; t < 8; ++t) acc[t] += v[t];
    }
  }

  float4 bv0 = *(const float4*)&bias[q * 8];
  float4 bv1 = *(const float4*)&bias[q * 8 + 4];
  float4 o0 = {bv0.x + d * acc[0], bv0.y + d * acc[1], bv0.z + d * acc[2],
               bv0.w + d * acc[3]};
  float4 o1 = {bv1.x + d * acc[4], bv1.y + d * acc[5], bv1.z + d * acc[6],
               bv1.w + d * acc[7]};
  *(float4*)&out[(long long)n * C + q * 8] = o0;
  *(float4*)&out[(long long)n * C + q * 8 + 4] = o1;
}

// ---------------- launch ----------------

extern "C" void kernel_launch(void* const* d_in, const int* in_sizes, int n_in,
                              void* d_out, int out_size, void* d_ws, size_t ws_size,
                              hipStream_t stream) {
  const float* x = (const float*)d_in[0];
  const int* ei = (const int*)d_in[1];
  const int* erow = ei;            // sources
  const int* ecol = ei + N_EDGES;  // targets
  const float* W1 = (const float*)d_in[2];
  const float* b1 = (const float*)d_in[3];
  const float* W2 = (const float*)d_in[4];
  const float* b2 = (const float*)d_in[5];
  float* out = (float*)d_out;

  char* ws = (char*)d_ws;
  int* deg = (int*)(ws + 0);                     // 400,000 B
  int* cursor = (int*)(ws + 400128);             // 400,000 B
  int* excl = (int*)(ws + 800256);               // 400,000 B
  int* bsum = (int*)(ws + 1200384);              // 512 B
  int* csr_src = (int*)(ws + 1200896);           // 2,560,000 B
  float* dinv = (float*)(ws + 3760896);          // 400,000 B
  unsigned short* hs1 = (unsigned short*)(ws + 4161024);  // 25.6 MB (bf16)
  unsigned short* hs2 = (unsigned short*)(ws + 29761024); // 12.8 MB (bf16)
  uint4* wfrag1 = (uint4*)(ws + 42561024);       // 32 KB
  uint4* wfrag2 = (uint4*)(ws + 42593792);       // 16 KB

  hipMemsetAsync(deg, 0, N_NODES * sizeof(int), stream);
  k_wprep_all<<<12, 256, 0, stream>>>(W1, W2, wfrag1, wfrag2);

  // CSR build
  k_hist<<<(N_EDGES + 255) / 256, 256, 0, stream>>>(ecol, deg);
  k_scan1<<<NSCANB, 256, 0, stream>>>(deg, excl, bsum);
  k_scan2<<<1, 128, 0, stream>>>(bsum);
  k_scan3<<<(N_NODES + 255) / 256, 256, 0, stream>>>(excl, bsum, deg, cursor, dinv);
  k_fill<<<(N_EDGES + 255) / 256, 256, 0, stream>>>(erow, ecol, cursor, csr_src);

  const int gblocks = (ROWTILES + 3) / 4;  // 1563

  // layer 1 GEMM -> hs1 (bf16)
  k_gemm1<<<gblocks, 256, 0, stream>>>(x, wfrag1, dinv, hs1);
  // fused layer-1 aggregation + layer-2 GEMM -> hs2 (bf16)
  k_gather_gemm2<<<gblocks, 256, 0, stream>>>(cursor, deg, csr_src, dinv, hs1, b1,
                                              wfrag2, hs2);
  // final aggregation -> out (f32)
  k_gather_out<<<N_NODES * 8 / 256, 256, 0, stream>>>(cursor, deg, csr_src, dinv, hs2,
                                                      b2, out);
}